// Round 11
// baseline (164.232 us; speedup 1.0000x reference)
//
#include <hip/hip_runtime.h>
#include <hip/hip_bf16.h>
#include <cstdint>

#define NHEAD 8
#define HD 32
#define DM 256
#define HH 56
#define WWID 56
#define HW 3136          // 56*56
#define NB 2
#define NTOT (NB * HW)   // 6272 positions (batch folded into GEMM N)
#define SCALE 0.17677669529663687f   // 32^-0.5
#define NBLK 512
#define GEN0 0x1357A000u
#define AGT __HIP_MEMORY_SCOPE_AGENT

typedef _Float16 f16;
typedef __attribute__((ext_vector_type(2))) _Float16 f16x2;
typedef __attribute__((ext_vector_type(8))) _Float16 f16x8;
typedef __attribute__((ext_vector_type(4))) float floatx4;

union U16 { uint4 u; f16x2 h2[4]; f16 h[8]; };

// ---------------------------------------------------------------------------
// Hierarchical grid barrier, CHEAP-SPIN version (R8 lesson: ACQUIRE-per-poll
// emits an L2 invalidate per iteration -> 512 spinners = ~70us/barrier).
// Here: arrivals use RELEASE RMWs (one L2 writeback each); spinners poll with
// RELAXED fetch_add(p,0) — RMWs always execute at the coherent point (m20:
// cross-XCD atomicAdd verified) — plus s_sleep backoff; ONE acquire fence
// (__builtin_amdgcn_fence; __hip_atomic_fence doesn't exist in this ROCm)
// after the generation flips. Layout (u32 idx in bar):
//   grpCnt[g]=g*32   grpGen[g]=1024+g*32   rootCnt=2048   rootGen=2080
// Co-residency of 512 blocks @ 27.6KB LDS/256thr proven by R8's completion.
// ---------------------------------------------------------------------------
__device__ __forceinline__ unsigned poll_rmw(unsigned* p) {
    return __hip_atomic_fetch_add(p, 0u, __ATOMIC_RELAXED, AGT);
}

__device__ __forceinline__ void gridsync(unsigned* bar, unsigned target) {
    __syncthreads();
    if (threadIdx.x == 0) {
        const int g = blockIdx.x >> 6;
        unsigned* grpCnt  = bar + g * 32;
        unsigned* grpGen  = bar + 1024 + g * 32;
        unsigned* rootCnt = bar + 2048;
        unsigned* rootGen = bar + 2080;
        if (__hip_atomic_fetch_add(grpCnt, 1u, __ATOMIC_RELEASE, AGT) == 63u) {
            __hip_atomic_store(grpCnt, 0u, __ATOMIC_RELAXED, AGT);
            if (__hip_atomic_fetch_add(rootCnt, 1u, __ATOMIC_RELEASE, AGT) == 7u) {
                __hip_atomic_store(rootCnt, 0u, __ATOMIC_RELAXED, AGT);
                __hip_atomic_store(rootGen, target, __ATOMIC_RELEASE, AGT);
            } else {
                while (poll_rmw(rootGen) != target) __builtin_amdgcn_s_sleep(4);
            }
            __hip_atomic_store(grpGen, target, __ATOMIC_RELEASE, AGT);
        } else {
            while (poll_rmw(grpGen) != target) __builtin_amdgcn_s_sleep(4);
        }
        __builtin_amdgcn_fence(__ATOMIC_ACQUIRE, "agent");   // one invalidate, post-pass
    }
    __syncthreads();
}

// ---------------------------------------------------------------------------
// GEMM phase (grid-stride). A f16 [M][256] k-contig; B [NTOT][256] k-contig.
// BM=128, BN=64, BK=64, 4 waves, wave = 64x32 via 4x2 16x16x32_f16.
// MODE 0: M=768 fused qkv -> q/k/v f16 [b][h][p][d], q pre-scaled by SCALE.
// MODE 1: M=256 out-proj -> fp32 d_out [b][c][p].
// ---------------------------------------------------------------------------
template<int MODE>
__device__ __forceinline__ void gemm_phase(
    const f16* __restrict__ A, const f16* __restrict__ Bm,
    const float* __restrict__ b0, const float* __restrict__ b1,
    const float* __restrict__ b2,
    f16* __restrict__ o0, f16* __restrict__ o1, f16* __restrict__ o2,
    float* __restrict__ yo,
    void* smem, int ntiles)
{
    f16 (*As)[72] = (f16(*)[72])smem;                      // 18432 B
    f16 (*Bs)[72] = (f16(*)[72])((char*)smem + 18432);     //  9216 B
    const int t = threadIdx.x;
    const int wave = t >> 6, lane = t & 63;
    const int quad = lane >> 4, l16 = lane & 15;
    const int mw = (wave & 1) * 64, nw = (wave >> 1) * 32;
    const int srow = t >> 3, suc = (t & 7) << 3;

    for (int tile = blockIdx.x; tile < ntiles; tile += NBLK) {
        const int mt = tile / 98, nt = tile - mt * 98;
        const int n0g = nt * 64, m0 = mt * 128;
        const int bb = n0g / HW, np = n0g - bb * HW;       // never straddles
        const f16* Bb = Bm + (size_t)n0g * DM;
        floatx4 acc[4][2] = {};
        for (int k0 = 0; k0 < DM; k0 += 64) {
            #pragma unroll
            for (int pp = 0; pp < 4; ++pp) {
                const int row = srow + pp * 32;
                *(uint4*)&As[row][suc] =
                    *(const uint4*)&A[(size_t)(m0 + row) * DM + k0 + suc];
            }
            #pragma unroll
            for (int pp = 0; pp < 2; ++pp) {
                const int row = srow + pp * 32;
                *(uint4*)&Bs[row][suc] =
                    *(const uint4*)&Bb[(size_t)row * DM + k0 + suc];
            }
            __syncthreads();
            #pragma unroll
            for (int ks = 0; ks < 2; ++ks) {
                f16x8 af[4], bf[2];
                #pragma unroll
                for (int mt2 = 0; mt2 < 4; ++mt2)
                    af[mt2] = *(const f16x8*)&As[mw + mt2 * 16 + l16][ks * 32 + quad * 8];
                #pragma unroll
                for (int nt2 = 0; nt2 < 2; ++nt2)
                    bf[nt2] = *(const f16x8*)&Bs[nw + nt2 * 16 + l16][ks * 32 + quad * 8];
                #pragma unroll
                for (int mt2 = 0; mt2 < 4; ++mt2)
                    #pragma unroll
                    for (int nt2 = 0; nt2 < 2; ++nt2)
                        acc[mt2][nt2] = __builtin_amdgcn_mfma_f32_16x16x32_f16(
                            af[mt2], bf[nt2], acc[mt2][nt2], 0, 0, 0);
            }
            __syncthreads();
        }
        if (MODE == 0) {
            #pragma unroll
            for (int mt2 = 0; mt2 < 4; ++mt2) {
                const int gm = m0 + mw + mt2 * 16 + quad * 4;
                const int proj = gm >> 8;
                const int c = gm & 255;
                const int h = c >> 5, d0 = c & 31;
                const float* bptr = proj == 0 ? b0 : (proj == 1 ? b1 : b2);
                f16* op = proj == 0 ? o0 : (proj == 1 ? o1 : o2);
                const float sc = proj == 0 ? SCALE : 1.0f;
                const size_t base = ((size_t)(bb * NHEAD + h) * HW) * HD + d0;
                float bias[4] = {bptr[c], bptr[c + 1], bptr[c + 2], bptr[c + 3]};
                #pragma unroll
                for (int nt2 = 0; nt2 < 2; ++nt2) {
                    const int p = np + nw + nt2 * 16 + l16;
                    union { ushort4 u; f16 h[4]; } pk;
                    #pragma unroll
                    for (int r = 0; r < 4; ++r)
                        pk.h[r] = (f16)((acc[mt2][nt2][r] + bias[r]) * sc);
                    *(ushort4*)&op[base + (size_t)p * HD] = pk.u;
                }
            }
        } else {
            #pragma unroll
            for (int mt2 = 0; mt2 < 4; ++mt2) {
                const int gc = m0 + mw + mt2 * 16 + quad * 4;
                #pragma unroll
                for (int r = 0; r < 4; ++r) {
                    const float bias = b0[gc + r];
                    #pragma unroll
                    for (int nt2 = 0; nt2 < 2; ++nt2) {
                        const int p = np + nw + nt2 * 16 + l16;
                        yo[(size_t)(bb * DM + gc + r) * HW + p] = acc[mt2][nt2][r] + bias;
                    }
                }
            }
        }
    }
}

// ---------------------------------------------------------------------------
// Fused persistent kernel: prep -> qkv GEMM -> window attention -> out GEMM,
// 3 cheap grid barriers. 512 blocks x 256 threads, 27.6 KB LDS arena.
// ---------------------------------------------------------------------------
__global__ __launch_bounds__(256) void fused_all(
    const float* __restrict__ x,
    const float* __restrict__ wq, const float* __restrict__ bq,
    const float* __restrict__ wk, const float* __restrict__ bk,
    const float* __restrict__ wv, const float* __restrict__ bv,
    const float* __restrict__ wo, const float* __restrict__ bo,
    f16* __restrict__ xT, f16* __restrict__ wcat, f16* __restrict__ wob,
    f16* __restrict__ qb, f16* __restrict__ kb, f16* __restrict__ vb,
    f16* __restrict__ attnT, float* __restrict__ out, unsigned* bar)
{
    __shared__ __align__(16) unsigned char smem[27648];
    const int bid = blockIdx.x, t = threadIdx.x;

    if (bid == 0 && t == 0) {      // init barrier state (ws poisoned each call)
        #pragma unroll
        for (int g = 0; g < 8; ++g)
            __hip_atomic_store(bar + g * 32, 0u, __ATOMIC_RELAXED, AGT);
        __hip_atomic_store(bar + 2048, 0u, __ATOMIC_RELAXED, AGT);
        __hip_atomic_store(bar + 2080, GEN0, __ATOMIC_RELEASE, AGT);
    }

    // ---------------- P0: x transpose (392 blocks) + weight convert ---------
    if (bid < 392) {
        float (*tile)[65] = (float(*)[65])smem;
        const int b = bid / 196, r = bid - b * 196;   // 4 c-tiles x 49 p-tiles
        const int ct = r / 49, pt = r - ct * 49;
        const int p0 = pt * 64, c0 = ct * 64;
        const float* xb = x + (size_t)b * DM * HW;
        #pragma unroll
        for (int i = 0; i < 4; ++i) {
            const int u = t + i * 256;
            const int rc = u >> 4, p4 = (u & 15) << 2;
            *(float4*)&tile[rc][p4] =
                *(const float4*)&xb[(size_t)(c0 + rc) * HW + p0 + p4];
        }
        __syncthreads();
        f16* xo = xT + (size_t)b * HW * DM;
        #pragma unroll
        for (int i = 0; i < 2; ++i) {
            const int u = t + i * 256;
            const int ch = u & 7, pq = u >> 3;
            U16 pk;
            #pragma unroll
            for (int kk = 0; kk < 8; ++kk)       // stride-65: conflict-free
                pk.h[kk] = (f16)tile[ch * 8 + kk][pq];
            *(uint4*)&xo[(size_t)(p0 + pq) * DM + c0 + ch * 8] = pk.u;
        }
    } else {
        for (int gid = (bid - 392) * 256 + t; gid < 65536; gid += 30720) {
            const int idx4 = gid << 2;
            const int sel = idx4 >> 16, off = idx4 & 65535;
            const float* src = sel == 0 ? wq : (sel == 1 ? wk : (sel == 2 ? wv : wo));
            f16* dst = sel < 3 ? (wcat + (sel << 16) + off) : (wob + off);
            float4 f = *(const float4*)&src[off];
            union { ushort4 u; f16 h[4]; } pk;
            pk.h[0] = (f16)f.x; pk.h[1] = (f16)f.y;
            pk.h[2] = (f16)f.z; pk.h[3] = (f16)f.w;
            *(ushort4*)dst = pk.u;
        }
    }
    // pre-gate: counters must be zeroed before first arrival (one RMW each,
    // init finished long ago — staggered, near-free)
    if (t == 0) {
        while (poll_rmw(bar + 2080) != GEN0) __builtin_amdgcn_s_sleep(4);
        __builtin_amdgcn_fence(__ATOMIC_ACQUIRE, "agent");
    }
    gridsync(bar, GEN0 + 1);

    // ---------------- P1: fused qkv GEMM (588 tiles) ------------------------
    gemm_phase<0>(wcat, xT, bq, bk, bv, qb, kb, vb, nullptr, smem, 588);
    gridsync(bar, GEN0 + 2);

    // ---------------- P2: window attention, 8x8 tiles (784) -----------------
    // 256 thr = 64 pos x 4 chunk-lanes; 14x14 zero-padded halo in LDS.
    // OOB slots true zeros -> exp(0)=1 joins the denominator automatically.
    {
        uint4* kh = (uint4*)smem;                       // 784 x 16B
        uint4* vh = (uint4*)(smem + 12544);             // 784 x 16B
        for (int tl = bid; tl < 784; tl += NBLK) {
            const int bh = tl / 49, r = tl - bh * 49;
            const int ry = r / 7;
            const int ty0 = ry * 8, tx0 = (r - ry * 7) * 8;
            const f16* kp = kb + (size_t)bh * HW * HD;
            const f16* vp = vb + (size_t)bh * HW * HD;
            __syncthreads();
            for (int u = t; u < 784; u += 256) {
                const int pos = u >> 2, ch = u & 3;
                const int hy = pos / 14, hx = pos - hy * 14;
                const int gy = ty0 + hy - 3, gx = tx0 + hx - 3;
                uint4 kv = make_uint4(0, 0, 0, 0), vv = make_uint4(0, 0, 0, 0);
                if ((unsigned)gy < HH && (unsigned)gx < WWID) {
                    const size_t g = (size_t)(gy * WWID + gx) * HD + (ch << 3);
                    kv = *(const uint4*)&kp[g];
                    vv = *(const uint4*)&vp[g];
                }
                kh[u] = kv; vh[u] = vv;
            }
            __syncthreads();
            const int pl = t >> 2, ch = t & 3;
            const int ty = pl >> 3, tx = pl & 7;
            const int p = (ty0 + ty) * WWID + tx0 + tx;
            U16 qu;
            qu.u = *(const uint4*)(qb + (size_t)bh * HW * HD + (size_t)p * HD + (ch << 3));
            const uint4* kbase = kh + (ty * 14 + tx) * 4 + ch;
            const uint4* vbase = vh + (ty * 14 + tx) * 4 + ch;
            float of[8] = {};
            float sum = 0.f;
            for (int i = 0; i < 7; ++i) {
                #pragma unroll
                for (int j = 0; j < 7; ++j) {
                    const int off = (i * 14 + j) << 2;
                    U16 ku; ku.u = kbase[off];
                    float s = __builtin_amdgcn_fdot2(ku.h2[0], qu.h2[0], 0.0f, false);
                    s = __builtin_amdgcn_fdot2(ku.h2[1], qu.h2[1], s, false);
                    s = __builtin_amdgcn_fdot2(ku.h2[2], qu.h2[2], s, false);
                    s = __builtin_amdgcn_fdot2(ku.h2[3], qu.h2[3], s, false);
                    s += __shfl_xor(s, 1);
                    s += __shfl_xor(s, 2);
                    const float e = __expf(s);
                    sum += e;
                    U16 vu; vu.u = vbase[off];
                    of[0] = fmaf((float)vu.h[0], e, of[0]);
                    of[1] = fmaf((float)vu.h[1], e, of[1]);
                    of[2] = fmaf((float)vu.h[2], e, of[2]);
                    of[3] = fmaf((float)vu.h[3], e, of[3]);
                    of[4] = fmaf((float)vu.h[4], e, of[4]);
                    of[5] = fmaf((float)vu.h[5], e, of[5]);
                    of[6] = fmaf((float)vu.h[6], e, of[6]);
                    of[7] = fmaf((float)vu.h[7], e, of[7]);
                }
            }
            const float inv = 1.0f / sum;
            f16* op = attnT + ((size_t)(bh >> 3) * HW + p) * DM
                            + (bh & 7) * HD + (ch << 3);
            U16 ou;
            #pragma unroll
            for (int j = 0; j < 8; ++j)
                ou.h[j] = (f16)(of[j] * inv);
            *(uint4*)op = ou.u;
        }
    }
    gridsync(bar, GEN0 + 3);

    // ---------------- P3: out projection (196 tiles) ------------------------
    gemm_phase<1>(wob, attnT, bo, nullptr, nullptr,
                  nullptr, nullptr, nullptr, out, smem, 196);
}

// ---------------------------------------------------------------------------
extern "C" void kernel_launch(void* const* d_in, const int* in_sizes, int n_in,
                              void* d_out, int out_size, void* d_ws, size_t ws_size,
                              hipStream_t stream) {
    const float* x  = (const float*)d_in[0];
    const float* wq = (const float*)d_in[1];
    const float* bq = (const float*)d_in[2];
    const float* wk = (const float*)d_in[3];
    const float* bk = (const float*)d_in[4];
    const float* wv = (const float*)d_in[5];
    const float* bv = (const float*)d_in[6];
    const float* wo = (const float*)d_in[7];
    const float* bo = (const float*)d_in[8];
    float* out = (float*)d_out;

    const size_t NPC = (size_t)NTOT * DM;
    f16* xT    = (f16*)d_ws;               // [b][p][c]
    f16* wcat  = xT + NPC;                 // [768][256]
    f16* wob   = wcat + 768 * 256;         // [256][256]
    f16* qb    = wob + 256 * 256;          // [b][h][p][d], q pre-scaled
    f16* kb    = qb + NPC;
    f16* vb    = kb + NPC;
    f16* attnT = vb + NPC;                 // [b][p][c]
    unsigned* bar = (unsigned*)(attnT + NPC);

    fused_all<<<NBLK, 256, 0, stream>>>(
        x, wq, bq, wk, bk, wv, bv, wo, bo,
        xT, wcat, wob, qb, kb, vb, attnT, out, bar);
}